// Round 9
// baseline (211.070 us; speedup 1.0000x reference)
//
#include <hip/hip_runtime.h>
#include <stdint.h>

#define NTOK 4096
#define NH 12
#define HDIM 64
#define DMODEL 768
#define D3 2304

typedef __attribute__((ext_vector_type(8))) __bf16 bf16x8;
typedef __attribute__((ext_vector_type(4))) float f32x4;
typedef __attribute__((ext_vector_type(4))) unsigned int u32x4;

#define MFMA(a, b, c) __builtin_amdgcn_mfma_f32_16x16x32_bf16((a), (b), (c), 0, 0, 0)

// round-half-up bf16 (0.5-ulp bound, same as RNE)
__device__ __forceinline__ uint16_t f2bf(float f) {
  uint32_t u = __builtin_bit_cast(uint32_t, f) + 0x8000u;
  return (uint16_t)(u >> 16);
}
// pack two floats -> two bf16 in one dword (a low, b high): 2 adds + 1 v_perm
__device__ __forceinline__ uint32_t packrd(float a, float b) {
  uint32_t ua = __builtin_bit_cast(uint32_t, a) + 0x8000u;
  uint32_t ub = __builtin_bit_cast(uint32_t, b) + 0x8000u;
  return __builtin_amdgcn_perm(ub, ua, 0x07060302u);
}
__device__ __forceinline__ float bf2f(uint16_t u) {
  uint32_t v = ((uint32_t)u) << 16;
  return __builtin_bit_cast(float, v);
}
// async global->LDS, 16B per lane; lds dest = wave-uniform base + lane*16
__device__ __forceinline__ void gld_lds16(const uint16_t* g, uint16_t* l) {
  __builtin_amdgcn_global_load_lds((const __attribute__((address_space(1))) void*)g,
                                   (__attribute__((address_space(3))) void*)l, 16, 0, 0);
}

// ---------------- cast hidden fp32 -> bf16 ----------------
__global__ void va_cast_bf16(const float* __restrict__ in, uint16_t* __restrict__ out, int n4) {
  int i = blockIdx.x * 256 + threadIdx.x;
  if (i >= n4) return;
  float4 v = ((const float4*)in)[i];
  ((uint2*)out)[i] = make_uint2(packrd(v.x, v.y), packrd(v.z, v.w));
}

// ---------------- transpose + cast: W[K][N] fp32 -> Wt[N][K] bf16 ----------------
__global__ void va_transpose_cast(const float* __restrict__ W, uint16_t* __restrict__ Wt,
                                  int K, int Ncols) {
  __shared__ uint16_t tile[32][36];
  const int t = threadIdx.x;
  const int k0 = blockIdx.y * 32, n0 = blockIdx.x * 32;
  {
    int i = t >> 3, j = (t & 7) * 4;
    float4 v = *(const float4*)(W + (size_t)(k0 + i) * Ncols + n0 + j);
    tile[i][j + 0] = f2bf(v.x);
    tile[i][j + 1] = f2bf(v.y);
    tile[i][j + 2] = f2bf(v.z);
    tile[i][j + 3] = f2bf(v.w);
  }
  __syncthreads();
  {
    int c = t >> 3, kk = (t & 7) * 4;
    uint32_t lo = (uint32_t)tile[kk + 0][c] | ((uint32_t)tile[kk + 1][c] << 16);
    uint32_t hi = (uint32_t)tile[kk + 2][c] | ((uint32_t)tile[kk + 3][c] << 16);
    *(uint2*)(Wt + (size_t)(n0 + c) * K + k0 + kk) = make_uint2(lo, hi);
  }
}

// ---------------- BK=64 GEMM: C = A[M][K] @ Bt[N][K]^T + bias ----------------
// k-tile of 64 split into two 64B-pitch LDS planes (keeps gld contiguity + m97 banking).
// MT=128: 4 waves 64x64. MT=64: 4 waves 64x32. Half the barriers of BK=32 at same gld count.
template <int MT, int OUT_BF16>
__global__ __launch_bounds__(256) void va_gemm64(const uint16_t* __restrict__ A,
                                                 const uint16_t* __restrict__ Bt,
                                                 const float* __restrict__ bias, void* Cout,
                                                 int M, int Nc, int K) {
  constexpr int NJ = (MT == 128) ? 4 : 2;
  __shared__ uint16_t As[2][MT * 32];
  __shared__ uint16_t Bs[2][128 * 32];
  const int t = threadIdx.x;
  const int w = t >> 6, ln = t & 63, quad = ln >> 4, l15 = ln & 15;
  const int m0 = blockIdx.y * MT, n0 = blockIdx.x * 128;
  const int wm = (MT == 128) ? (w & 1) * 64 : 0;
  const int wn = (MT == 128) ? (w >> 1) * 64 : w * 32;
  const int srow = w * 16 + (ln >> 2), schunk = (ln & 3) * 8;  // 64 rows x 4x16B per gld
  f32x4 acc[4][NJ] = {};
  for (int kk = 0; kk < K; kk += 64) {
#pragma unroll
    for (int p = 0; p < 2; ++p) {  // k-plane
#pragma unroll
      for (int hh = 0; hh < MT / 64; ++hh)
        gld_lds16(A + (size_t)(m0 + hh * 64 + srow) * K + kk + p * 32 + schunk,
                  &As[p][(hh * 64 + w * 16) * 32]);
#pragma unroll
      for (int hh = 0; hh < 2; ++hh)
        gld_lds16(Bt + (size_t)(n0 + hh * 64 + srow) * K + kk + p * 32 + schunk,
                  &Bs[p][(hh * 64 + w * 16) * 32]);
    }
    __syncthreads();
#pragma unroll
    for (int ko = 0; ko < 2; ++ko) {
      bf16x8 af[4], bfr[NJ];
#pragma unroll
      for (int i = 0; i < 4; ++i)
        af[i] = *(const bf16x8*)(&As[ko][(wm + i * 16 + l15) * 32 + quad * 8]);
#pragma unroll
      for (int j = 0; j < NJ; ++j)
        bfr[j] = *(const bf16x8*)(&Bs[ko][(wn + j * 16 + l15) * 32 + quad * 8]);
#pragma unroll
      for (int i = 0; i < 4; ++i)
#pragma unroll
        for (int j = 0; j < NJ; ++j) acc[i][j] = MFMA(af[i], bfr[j], acc[i][j]);
    }
    __syncthreads();
  }
#pragma unroll
  for (int i = 0; i < 4; ++i) {
    int row = m0 + wm + i * 16 + quad * 4;
#pragma unroll
    for (int j = 0; j < NJ; ++j) {
      int col = n0 + wn + j * 16 + l15;
      float b = bias[col];
      if (OUT_BF16) {
        uint16_t* C = (uint16_t*)Cout;
#pragma unroll
        for (int rg = 0; rg < 4; ++rg) C[(size_t)(row + rg) * Nc + col] = f2bf(acc[i][j][rg] + b);
      } else {
        float* C = (float*)Cout;
#pragma unroll
        for (int rg = 0; rg < 4; ++rg) C[(size_t)(row + rg) * Nc + col] = acc[i][j][rg] + b;
      }
    }
  }
}

// ---------------- RoPE + layout split (bf16 in) ----------------
// V stored in TWO PLANES by key-half of the free-P permutation:
// token lane L -> plane H=(L>>4)&1, pos = ((L>>2)&3)*8 + ((L>>5)&1)*4 + (L&3)
// plane layout: Vtg[((H*NH+h)*HDIM + d)*2048 + win*32 + pos]
__global__ void va_rope_split(const uint16_t* __restrict__ qkvb, const float* __restrict__ cosb,
                              const float* __restrict__ sinb, uint16_t* __restrict__ Qg,
                              uint16_t* __restrict__ Kg, uint16_t* __restrict__ Vtg) {
  const int h = blockIdx.y;
  const int lane = threadIdx.x & 63;
  const int c = threadIdx.x >> 6;
  const int n = blockIdx.x * 64 + lane;
  const uint16_t* base = qkvb + (size_t)n * D3 + h * HDIM;
  const float QS = 0.125f * 1.4426950408889634f;
  float c0[8], s0[8], c1[8], s1[8];
  *(float4*)(c0) = *(const float4*)(cosb + (size_t)n * HDIM + c * 8);
  *(float4*)(c0 + 4) = *(const float4*)(cosb + (size_t)n * HDIM + c * 8 + 4);
  *(float4*)(s0) = *(const float4*)(sinb + (size_t)n * HDIM + c * 8);
  *(float4*)(s0 + 4) = *(const float4*)(sinb + (size_t)n * HDIM + c * 8 + 4);
  *(float4*)(c1) = *(const float4*)(cosb + (size_t)n * HDIM + c * 8 + 32);
  *(float4*)(c1 + 4) = *(const float4*)(cosb + (size_t)n * HDIM + c * 8 + 36);
  *(float4*)(s1) = *(const float4*)(sinb + (size_t)n * HDIM + c * 8 + 32);
  *(float4*)(s1 + 4) = *(const float4*)(sinb + (size_t)n * HDIM + c * 8 + 36);
#pragma unroll
  for (int mtx = 0; mtx < 2; ++mtx) {
    const uint16_t* src = base + mtx * DMODEL;
    uint16_t* dst = (mtx ? Kg : Qg) + ((size_t)h * NTOK + n) * HDIM;
    const float sc = mtx ? 1.0f : QS;
    uint16_t lo[8], hi[8];
    *(uint4*)lo = *(const uint4*)(src + c * 8);
    *(uint4*)hi = *(const uint4*)(src + c * 8 + 32);
    uint32_t outlo[4], outhi[4];
#pragma unroll
    for (int j = 0; j < 8; j += 2) {
      float x0 = bf2f(lo[j]), x1 = bf2f(lo[j + 1]);
      float y0 = bf2f(hi[j]), y1 = bf2f(hi[j + 1]);
      float a0 = (x0 * c0[j] - y0 * s0[j]) * sc;
      float a1 = (x1 * c0[j + 1] - y1 * s0[j + 1]) * sc;
      float b0 = (y0 * c1[j] + x0 * s1[j]) * sc;
      float b1 = (y1 * c1[j + 1] + x1 * s1[j + 1]) * sc;
      outlo[j >> 1] = packrd(a0, a1);
      outhi[j >> 1] = packrd(b0, b1);
    }
    *(uint4*)(dst + c * 8) = *(uint4*)outlo;
    *(uint4*)(dst + c * 8 + 32) = *(uint4*)outhi;
  }
  // split-plane permuted V store
  const int H = (lane >> 4) & 1;
  const int pos = ((lane >> 2) & 3) * 8 + ((lane >> 5) & 1) * 4 + (lane & 3);
  const int col = blockIdx.x * 32 + pos;
  uint16_t vv[16];
  *(uint4*)(vv) = *(const uint4*)(base + 2 * DMODEL + c * 16);
  *(uint4*)(vv + 8) = *(const uint4*)(base + 2 * DMODEL + c * 16 + 8);
#pragma unroll
  for (int j = 0; j < 16; ++j)
    Vtg[(((size_t)H * NH + h) * HDIM + c * 16 + j) * 2048 + col] = vv[j];
}

// ---------------- Flash attention v9: free P transform + l via ones-MFMA ----------------
// Grid: x = qb(32) | ks(2)<<5, y = head. 768 blocks = 3/CU exactly. 32 iters of 64-key tiles.
// PV key order kappa(k=quad*8+e, H) = 32*(e>>2) + 16H + quad*4 + (e&3):
//   - P B-operand dwords == QK C-layout packed dwords (same lane), zero-cost transform
//   - V A-operand == contiguous b128 from VsH (plane split done in rope)
// l computed by ones-row MFMA (every C row of ones*P = column sum) -> no scalar adds/shuffles.
__global__ __launch_bounds__(256, 3) void va_flash9(const uint16_t* __restrict__ Qg,
                                                    const uint16_t* __restrict__ Kg,
                                                    const uint16_t* __restrict__ Vtg,
                                                    uint16_t* __restrict__ Opb,
                                                    float* __restrict__ Lp) {
  __shared__ uint16_t Ks[2][2][64 * 32];  // [dbuf][d-half][64 keys x 32 d]
  __shared__ uint16_t Vs[2][2][64 * 32];  // [dbuf][key-plane H][64 d x 32 permuted keys]
  const int t = threadIdx.x;
  const int w = t >> 6, ln = t & 63, quad = ln >> 4, l15 = ln & 15;
  const int h = blockIdx.y;
  const int qb = blockIdx.x & 31, ks = blockIdx.x >> 5;
  const int q0 = qb * 128, key0 = ks * 2048;

  bf16x8 qf[2][2];
#pragma unroll
  for (int s = 0; s < 2; ++s)
#pragma unroll
    for (int c = 0; c < 2; ++c)
      qf[s][c] = *(const bf16x8*)(Qg + ((size_t)h * NTOK + q0 + w * 32 + s * 16 + l15) * HDIM +
                                  c * 32 + quad * 8);
  const u32x4 onesu = {0x3F803F80u, 0x3F803F80u, 0x3F803F80u, 0x3F803F80u};
  const bf16x8 vones = __builtin_bit_cast(bf16x8, onesu);
  f32x4 o[2][4] = {};
  f32x4 ol[2] = {};  // ones-MFMA accumulator: all regs hold l[query l15]
  // staging pointers (strength-reduced in loop)
  const uint16_t* Kst =
      Kg + ((size_t)h * NTOK + key0 + w * 16 + (ln >> 2)) * HDIM + (ln & 3) * 8;
  const uint16_t* Vst0 =
      Vtg + (((size_t)0 * NH + h) * HDIM + w * 16 + (ln >> 2)) * 2048 + ks * 1024 + (ln & 3) * 8;
  const uint16_t* Vst1 =
      Vtg + (((size_t)1 * NH + h) * HDIM + w * 16 + (ln >> 2)) * 2048 + ks * 1024 + (ln & 3) * 8;

  gld_lds16(Kst, &Ks[0][0][w * 16 * 32]);
  gld_lds16(Kst + 32, &Ks[0][1][w * 16 * 32]);
  gld_lds16(Vst0, &Vs[0][0][w * 16 * 32]);
  gld_lds16(Vst1, &Vs[0][1][w * 16 * 32]);

  for (int kt = 0; kt < 32; ++kt) {
    __syncthreads();  // gld into buf cur complete; reads of buf cur^1 done
    const int cur = kt & 1;
    if (kt < 31) {
      Kst += 64 * HDIM;
      Vst0 += 32;
      Vst1 += 32;
      gld_lds16(Kst, &Ks[cur ^ 1][0][w * 16 * 32]);
      gld_lds16(Kst + 32, &Ks[cur ^ 1][1][w * 16 * 32]);
      gld_lds16(Vst0, &Vs[cur ^ 1][0][w * 16 * 32]);
      gld_lds16(Vst1, &Vs[cur ^ 1][1][w * 16 * 32]);
    }
    // QK^T: st[s][mt] keys mt*16+quad*4+rg, query s*16+l15 (C layout)
    f32x4 st[2][4];
#pragma unroll
    for (int mt = 0; mt < 4; ++mt) {
      bf16x8 ka0 = *(const bf16x8*)(&Ks[cur][0][(mt * 16 + l15) * 32 + quad * 8]);
      bf16x8 ka1 = *(const bf16x8*)(&Ks[cur][1][(mt * 16 + l15) * 32 + quad * 8]);
#pragma unroll
      for (int s = 0; s < 2; ++s) {
        f32x4 z = {};
        z = MFMA(ka0, qf[s][0], z);
        st[s][mt] = MFMA(ka1, qf[s][1], z);
      }
    }
    // V fragments: contiguous b128 from VsH (64B pitch, Ks-class banking)
    bf16x8 vf[4][2];
#pragma unroll
    for (int dt = 0; dt < 4; ++dt)
#pragma unroll
      for (int H = 0; H < 2; ++H)
        vf[dt][H] = *(const bf16x8*)(&Vs[cur][H][(dt * 16 + l15) * 32 + quad * 8]);
#pragma unroll
    for (int s = 0; s < 2; ++s) {
      uint32_t Ppk[4][2];
#pragma unroll
      for (int mt = 0; mt < 4; ++mt) {
        float p0 = __builtin_amdgcn_exp2f(st[s][mt][0]);
        float p1 = __builtin_amdgcn_exp2f(st[s][mt][1]);
        float p2 = __builtin_amdgcn_exp2f(st[s][mt][2]);
        float p3 = __builtin_amdgcn_exp2f(st[s][mt][3]);
        Ppk[mt][0] = packrd(p0, p1);
        Ppk[mt][1] = packrd(p2, p3);
      }
#pragma unroll
      for (int H = 0; H < 2; ++H) {
        u32x4 d = {Ppk[H][0], Ppk[H][1], Ppk[H + 2][0], Ppk[H + 2][1]};
        bf16x8 pf = __builtin_bit_cast(bf16x8, d);
#pragma unroll
        for (int dt = 0; dt < 4; ++dt) o[s][dt] = MFMA(vf[dt][H], pf, o[s][dt]);
        ol[s] = MFMA(vones, pf, ol[s]);
      }
    }
  }
  // epilogue: store unnormalized O^T bf16 + per-query l (fp32, from ones-MFMA acc)
  uint16_t* ob = Opb + ((size_t)(ks * NH + h) * HDIM) * NTOK;
#pragma unroll
  for (int s = 0; s < 2; ++s) {
    int q = q0 + w * 32 + s * 16 + l15;
#pragma unroll
    for (int dt = 0; dt < 4; ++dt)
#pragma unroll
      for (int rg = 0; rg < 4; ++rg)
        ob[(size_t)(dt * 16 + quad * 4 + rg) * NTOK + q] = f2bf(o[s][dt][rg]);
    if (quad == 0) Lp[(size_t)(ks * NH + h) * NTOK + q] = ol[s][0];
  }
}

// ---------------- combine 2 key-splits, normalize, write bf16 [n][h*64+d] ----------------
__global__ __launch_bounds__(256) void va_combine2(const uint16_t* __restrict__ Opb,
                                                   const float* __restrict__ Lp,
                                                   uint16_t* __restrict__ Ob) {
  __shared__ uint16_t T[64][72];
  const int h = blockIdx.y;
  const int n0 = blockIdx.x * 64;
  const int t = threadIdx.x;
  const int lane = t & 63, c = t >> 6;
  const int n = n0 + lane;
  float lsum = Lp[(size_t)h * NTOK + n] + Lp[(size_t)(NH + h) * NTOK + n];
  const float inv = 1.0f / lsum;
#pragma unroll
  for (int j = 0; j < 16; j += 2) {
    int d = c * 16 + j;
    float r0 = 0.f, r1 = 0.f;
#pragma unroll
    for (int s = 0; s < 2; ++s) {
      const uint16_t* p = Opb + ((size_t)(s * NH + h) * HDIM + d) * NTOK + n;
      r0 += bf2f(p[0]);
      r1 += bf2f(p[NTOK]);
    }
    *(uint32_t*)(&T[lane][d]) = packrd(r0 * inv, r1 * inv);
  }
  __syncthreads();
  const int row = t >> 2, ch = t & 3;
  uint4 a = *(const uint4*)(&T[row][ch * 16]);
  uint4 b = *(const uint4*)(&T[row][ch * 16 + 8]);
  uint16_t* dst = Ob + (size_t)(n0 + row) * DMODEL + h * HDIM + ch * 16;
  *(uint4*)dst = a;
  *(uint4*)(dst + 8) = b;
}

extern "C" void kernel_launch(void* const* d_in, const int* in_sizes, int n_in, void* d_out,
                              int out_size, void* d_ws, size_t ws_size, hipStream_t stream) {
  (void)in_sizes; (void)n_in; (void)out_size; (void)ws_size;
  const float* hidden = (const float*)d_in[0];
  const float* cosb = (const float*)d_in[1];
  const float* sinb = (const float*)d_in[2];
  const float* qkv_w = (const float*)d_in[3];
  const float* qkv_b = (const float*)d_in[4];
  const float* proj_w = (const float*)d_in[5];
  const float* proj_b = (const float*)d_in[6];
  float* out = (float*)d_out;

  char* ws = (char*)d_ws;
  size_t off = 0;
  auto alloc = [&](size_t bytes) {
    void* p = ws + off;
    off += (bytes + 255) & ~(size_t)255;
    return p;
  };
  uint16_t* Abf = (uint16_t*)alloc((size_t)NTOK * DMODEL * 2);
  uint16_t* Wqt = (uint16_t*)alloc((size_t)D3 * DMODEL * 2);
  uint16_t* Wpt = (uint16_t*)alloc((size_t)DMODEL * DMODEL * 2);
  uint16_t* qkvb = (uint16_t*)alloc((size_t)NTOK * D3 * 2);
  uint16_t* Qb = (uint16_t*)alloc((size_t)NH * NTOK * HDIM * 2);
  uint16_t* Kb = (uint16_t*)alloc((size_t)NH * NTOK * HDIM * 2);
  uint16_t* Vtb = (uint16_t*)alloc((size_t)2 * NH * HDIM * 2048 * 2);  // split planes
  uint16_t* Ob = (uint16_t*)alloc((size_t)NTOK * DMODEL * 2);
  uint16_t* Opb = (uint16_t*)alloc((size_t)2 * NH * HDIM * NTOK * 2);
  float* Lp = (float*)alloc((size_t)2 * NH * NTOK * 4);

  va_cast_bf16<<<(NTOK * DMODEL / 4 + 255) / 256, 256, 0, stream>>>(hidden, Abf,
                                                                    NTOK * DMODEL / 4);
  va_transpose_cast<<<dim3(D3 / 32, DMODEL / 32), 256, 0, stream>>>(qkv_w, Wqt, DMODEL, D3);
  va_transpose_cast<<<dim3(DMODEL / 32, DMODEL / 32), 256, 0, stream>>>(proj_w, Wpt, DMODEL,
                                                                        DMODEL);
  va_gemm64<128, 1><<<dim3(D3 / 128, NTOK / 128), 256, 0, stream>>>(Abf, Wqt, qkv_b, qkvb, NTOK,
                                                                    D3, DMODEL);
  va_rope_split<<<dim3(NTOK / 64, NH), 256, 0, stream>>>(qkvb, cosb, sinb, Qb, Kb, Vtb);
  va_flash9<<<dim3(64, NH), 256, 0, stream>>>(Qb, Kb, Vtb, Opb, Lp);
  va_combine2<<<dim3(NTOK / 64, NH), 256, 0, stream>>>(Opb, Lp, Ob);
  va_gemm64<64, 0><<<dim3(DMODEL / 128, NTOK / 64), 256, 0, stream>>>(Ob, Wpt, proj_b, out, NTOK,
                                                                      DMODEL, DMODEL);
}

// Round 10
// 200.195 us; speedup vs baseline: 1.0543x; 1.0543x over previous
//
#include <hip/hip_runtime.h>
#include <stdint.h>

#define NTOK 4096
#define NH 12
#define HDIM 64
#define DMODEL 768
#define D3 2304

typedef __attribute__((ext_vector_type(8))) __bf16 bf16x8;
typedef __attribute__((ext_vector_type(4))) float f32x4;
typedef __attribute__((ext_vector_type(4))) unsigned int u32x4;

#define MFMA(a, b, c) __builtin_amdgcn_mfma_f32_16x16x32_bf16((a), (b), (c), 0, 0, 0)

// round-half-up bf16 (0.5-ulp bound, same as RNE)
__device__ __forceinline__ uint16_t f2bf(float f) {
  uint32_t u = __builtin_bit_cast(uint32_t, f) + 0x8000u;
  return (uint16_t)(u >> 16);
}
// pack two floats -> two bf16 in one dword, round-half-up: 2 adds + 1 v_perm
__device__ __forceinline__ uint32_t packrd(float a, float b) {
  uint32_t ua = __builtin_bit_cast(uint32_t, a) + 0x8000u;
  uint32_t ub = __builtin_bit_cast(uint32_t, b) + 0x8000u;
  return __builtin_amdgcn_perm(ub, ua, 0x07060302u);
}
// pack two floats -> two bf16, TRUNCATE (1 op). Used for P only: P in [0,1] and the
// l-sum uses the same truncated pf, so the downward bias cancels in O/l to 1st order.
__device__ __forceinline__ uint32_t packtr(float a, float b) {
  return __builtin_amdgcn_perm(__builtin_bit_cast(uint32_t, b), __builtin_bit_cast(uint32_t, a),
                               0x07060302u);
}
__device__ __forceinline__ float bf2f(uint16_t u) {
  uint32_t v = ((uint32_t)u) << 16;
  return __builtin_bit_cast(float, v);
}
// async global->LDS, 16B per lane; lds dest = wave-uniform base + lane*16
__device__ __forceinline__ void gld_lds16(const uint16_t* g, uint16_t* l) {
  __builtin_amdgcn_global_load_lds((const __attribute__((address_space(1))) void*)g,
                                   (__attribute__((address_space(3))) void*)l, 16, 0, 0);
}

// ---------------- cast hidden fp32 -> bf16 ----------------
__global__ void va_cast_bf16(const float* __restrict__ in, uint16_t* __restrict__ out, int n4) {
  int i = blockIdx.x * 256 + threadIdx.x;
  if (i >= n4) return;
  float4 v = ((const float4*)in)[i];
  ((uint2*)out)[i] = make_uint2(packrd(v.x, v.y), packrd(v.z, v.w));
}

// ---------------- transpose + cast: W[K][N] fp32 -> Wt[N][K] bf16 ----------------
__global__ void va_transpose_cast(const float* __restrict__ W, uint16_t* __restrict__ Wt,
                                  int K, int Ncols) {
  __shared__ uint16_t tile[32][36];
  const int t = threadIdx.x;
  const int k0 = blockIdx.y * 32, n0 = blockIdx.x * 32;
  {
    int i = t >> 3, j = (t & 7) * 4;
    float4 v = *(const float4*)(W + (size_t)(k0 + i) * Ncols + n0 + j);
    tile[i][j + 0] = f2bf(v.x);
    tile[i][j + 1] = f2bf(v.y);
    tile[i][j + 2] = f2bf(v.z);
    tile[i][j + 3] = f2bf(v.w);
  }
  __syncthreads();
  {
    int c = t >> 3, kk = (t & 7) * 4;
    uint32_t lo = (uint32_t)tile[kk + 0][c] | ((uint32_t)tile[kk + 1][c] << 16);
    uint32_t hi = (uint32_t)tile[kk + 2][c] | ((uint32_t)tile[kk + 3][c] << 16);
    *(uint2*)(Wt + (size_t)(n0 + c) * K + k0 + kk) = make_uint2(lo, hi);
  }
}

// ---------------- fused QKV GEMM + RoPE + V-plane-permute ----------------
// m97 structure (128x128 tile, BK=32, gld_lds16). Epilogue by column-block type:
//   Q cols 0..767 / K cols 768..1535: RoPE in-register (pair (d,d+32) = acc[i][j] &
//   acc[i][j+2], same lane), write Qg/Kg [h][n][64]. Q also folds SCALE*log2e.
//   V cols 1536..2303: plane-permuted store, H=i&1, pos=quad*8+((i>>1)&1)*4+rg ->
//   rg-contiguous packed uint2 stores into Vtg[((H*NH+h)*64+d)*2048 + win*32 + pos].
__global__ __launch_bounds__(256) void va_gemm_qkv(const uint16_t* __restrict__ A,
                                                   const uint16_t* __restrict__ Bt,
                                                   const float* __restrict__ bias,
                                                   const float* __restrict__ cosb,
                                                   const float* __restrict__ sinb,
                                                   uint16_t* __restrict__ Qg,
                                                   uint16_t* __restrict__ Kg,
                                                   uint16_t* __restrict__ Vtg) {
  __shared__ uint16_t As[128 * 32];
  __shared__ uint16_t Bs[128 * 32];
  const int t = threadIdx.x;
  const int w = t >> 6, ln = t & 63, quad = ln >> 4, l15 = ln & 15;
  const int m0 = blockIdx.y * 128, n0 = blockIdx.x * 128;
  const int wm = (w & 1) * 64, wn = (w >> 1) * 64;
  const int srow = t >> 2, scol = (t & 3) * 8;
  f32x4 acc[4][4] = {};
  for (int kk = 0; kk < DMODEL; kk += 32) {
#pragma unroll
    for (int p = 0; p < 2; ++p) {
      gld_lds16(A + (size_t)(m0 + p * 64 + srow) * DMODEL + kk + scol,
                As + (p * 64 + w * 16) * 32);
      gld_lds16(Bt + (size_t)(n0 + p * 64 + srow) * DMODEL + kk + scol,
                Bs + (p * 64 + w * 16) * 32);
    }
    __syncthreads();
    bf16x8 af[4], bfr[4];
#pragma unroll
    for (int i = 0; i < 4; ++i) {
      af[i] = *(const bf16x8*)(As + (wm + i * 16 + l15) * 32 + quad * 8);
      bfr[i] = *(const bf16x8*)(Bs + (wn + i * 16 + l15) * 32 + quad * 8);
    }
#pragma unroll
    for (int i = 0; i < 4; ++i)
#pragma unroll
      for (int j = 0; j < 4; ++j) acc[i][j] = MFMA(af[i], bfr[j], acc[i][j]);
    __syncthreads();
  }
  const int col0 = n0 + wn;          // multiple of 64
  const int type = col0 / DMODEL;    // 0=Q 1=K 2=V
  const int h = (col0 % DMODEL) / HDIM;
  if (type < 2) {
    const float sc = (type == 0) ? (0.125f * 1.4426950408889634f) : 1.0f;
    uint16_t* dst = (type == 0 ? Qg : Kg) + (size_t)h * NTOK * HDIM;
#pragma unroll
    for (int j = 0; j < 2; ++j) {
      const int d = j * 16 + l15, dhi = d + 32;
      const float blo = bias[col0 + d], bhi = bias[col0 + dhi];
#pragma unroll
      for (int i = 0; i < 4; ++i) {
        const int row0 = m0 + wm + i * 16 + quad * 4;
#pragma unroll
        for (int rg = 0; rg < 4; ++rg) {
          const int n = row0 + rg;
          const float a = acc[i][j][rg] + blo;
          const float b = acc[i][j + 2][rg] + bhi;
          const float cl = cosb[(size_t)n * HDIM + d], sl = sinb[(size_t)n * HDIM + d];
          const float ch = cosb[(size_t)n * HDIM + dhi], sh = sinb[(size_t)n * HDIM + dhi];
          dst[(size_t)n * HDIM + d] = f2bf((a * cl - b * sl) * sc);
          dst[(size_t)n * HDIM + dhi] = f2bf((b * ch + a * sh) * sc);
        }
      }
    }
  } else {
    const int win = (m0 + wm) >> 6;
#pragma unroll
    for (int i = 0; i < 4; ++i) {
      const int H = i & 1, hb = (i >> 1) & 1;
      const int colp = win * 32 + quad * 8 + hb * 4;
#pragma unroll
      for (int j = 0; j < 4; ++j) {
        const int d = j * 16 + l15;
        const float bb = bias[col0 + d];
        uint32_t u0 = packrd(acc[i][j][0] + bb, acc[i][j][1] + bb);
        uint32_t u1 = packrd(acc[i][j][2] + bb, acc[i][j][3] + bb);
        *(uint2*)(Vtg + (((size_t)H * NH + h) * HDIM + d) * 2048 + colp) = make_uint2(u0, u1);
      }
    }
  }
}

// ---------------- m97-style GEMM (proj): C = A @ Bt^T + bias, fp32 out ----------------
__global__ __launch_bounds__(256) void va_gemm_proj(const uint16_t* __restrict__ A,
                                                    const uint16_t* __restrict__ Bt,
                                                    const float* __restrict__ bias,
                                                    float* __restrict__ C, int M, int Nc, int K) {
  __shared__ uint16_t As[64 * 32];
  __shared__ uint16_t Bs[128 * 32];
  const int t = threadIdx.x;
  const int w = t >> 6, ln = t & 63, quad = ln >> 4, l15 = ln & 15;
  const int m0 = blockIdx.y * 64, n0 = blockIdx.x * 128;
  const int wn = w * 32;
  const int srow = t >> 2, scol = (t & 3) * 8;
  f32x4 acc[4][2] = {};
  for (int kk = 0; kk < K; kk += 32) {
    if (srow < 64)
      gld_lds16(A + (size_t)(m0 + srow) * K + kk + scol, As + w * 16 * 32);
#pragma unroll
    for (int p = 0; p < 2; ++p)
      gld_lds16(Bt + (size_t)(n0 + p * 64 + srow) * K + kk + scol, Bs + (p * 64 + w * 16) * 32);
    __syncthreads();
    bf16x8 af[4], bfr[2];
#pragma unroll
    for (int i = 0; i < 4; ++i) af[i] = *(const bf16x8*)(As + (i * 16 + l15) * 32 + quad * 8);
#pragma unroll
    for (int j = 0; j < 2; ++j)
      bfr[j] = *(const bf16x8*)(Bs + (wn + j * 16 + l15) * 32 + quad * 8);
#pragma unroll
    for (int i = 0; i < 4; ++i)
#pragma unroll
      for (int j = 0; j < 2; ++j) acc[i][j] = MFMA(af[i], bfr[j], acc[i][j]);
    __syncthreads();
  }
#pragma unroll
  for (int i = 0; i < 4; ++i) {
    int row = m0 + i * 16 + quad * 4;
#pragma unroll
    for (int j = 0; j < 2; ++j) {
      int col = n0 + wn + j * 16 + l15;
      float b = bias[col];
#pragma unroll
      for (int rg = 0; rg < 4; ++rg) C[(size_t)(row + rg) * Nc + col] = acc[i][j][rg] + b;
    }
  }
}

// ---------------- Flash attention v10: free P transform + l via ones-MFMA -------------
// Grid: x = qb(32) | ks(2)<<5, y = head. 768 blocks = 3/CU exactly. 32 iters of 64-key tiles.
__global__ __launch_bounds__(256, 3) void va_flash10(const uint16_t* __restrict__ Qg,
                                                     const uint16_t* __restrict__ Kg,
                                                     const uint16_t* __restrict__ Vtg,
                                                     uint16_t* __restrict__ Opb,
                                                     float* __restrict__ Lp) {
  __shared__ uint16_t Ks[2][2][64 * 32];  // [dbuf][d-half][64 keys x 32 d]
  __shared__ uint16_t Vs[2][2][64 * 32];  // [dbuf][key-plane H][64 d x 32 permuted keys]
  const int t = threadIdx.x;
  const int w = t >> 6, ln = t & 63, quad = ln >> 4, l15 = ln & 15;
  const int h = blockIdx.y;
  const int qb = blockIdx.x & 31, ks = blockIdx.x >> 5;
  const int q0 = qb * 128, key0 = ks * 2048;

  bf16x8 qf[2][2];
#pragma unroll
  for (int s = 0; s < 2; ++s)
#pragma unroll
    for (int c = 0; c < 2; ++c)
      qf[s][c] = *(const bf16x8*)(Qg + ((size_t)h * NTOK + q0 + w * 32 + s * 16 + l15) * HDIM +
                                  c * 32 + quad * 8);
  const u32x4 onesu = {0x3F803F80u, 0x3F803F80u, 0x3F803F80u, 0x3F803F80u};
  const bf16x8 vones = __builtin_bit_cast(bf16x8, onesu);
  f32x4 o[2][4] = {};
  f32x4 ol[2] = {};  // ones-MFMA accumulator: all regs hold l[query l15]
  const uint16_t* Kst =
      Kg + ((size_t)h * NTOK + key0 + w * 16 + (ln >> 2)) * HDIM + (ln & 3) * 8;
  const uint16_t* Vst0 =
      Vtg + (((size_t)0 * NH + h) * HDIM + w * 16 + (ln >> 2)) * 2048 + ks * 1024 + (ln & 3) * 8;
  const uint16_t* Vst1 =
      Vtg + (((size_t)1 * NH + h) * HDIM + w * 16 + (ln >> 2)) * 2048 + ks * 1024 + (ln & 3) * 8;

  gld_lds16(Kst, &Ks[0][0][w * 16 * 32]);
  gld_lds16(Kst + 32, &Ks[0][1][w * 16 * 32]);
  gld_lds16(Vst0, &Vs[0][0][w * 16 * 32]);
  gld_lds16(Vst1, &Vs[0][1][w * 16 * 32]);

  for (int kt = 0; kt < 32; ++kt) {
    __syncthreads();
    const int cur = kt & 1;
    if (kt < 31) {
      Kst += 64 * HDIM;
      Vst0 += 32;
      Vst1 += 32;
      gld_lds16(Kst, &Ks[cur ^ 1][0][w * 16 * 32]);
      gld_lds16(Kst + 32, &Ks[cur ^ 1][1][w * 16 * 32]);
      gld_lds16(Vst0, &Vs[cur ^ 1][0][w * 16 * 32]);
      gld_lds16(Vst1, &Vs[cur ^ 1][1][w * 16 * 32]);
    }
    f32x4 st[2][4];
#pragma unroll
    for (int mt = 0; mt < 4; ++mt) {
      bf16x8 ka0 = *(const bf16x8*)(&Ks[cur][0][(mt * 16 + l15) * 32 + quad * 8]);
      bf16x8 ka1 = *(const bf16x8*)(&Ks[cur][1][(mt * 16 + l15) * 32 + quad * 8]);
#pragma unroll
      for (int s = 0; s < 2; ++s) {
        f32x4 z = {};
        z = MFMA(ka0, qf[s][0], z);
        st[s][mt] = MFMA(ka1, qf[s][1], z);
      }
    }
    bf16x8 vf[4][2];
#pragma unroll
    for (int dt = 0; dt < 4; ++dt)
#pragma unroll
      for (int H = 0; H < 2; ++H)
        vf[dt][H] = *(const bf16x8*)(&Vs[cur][H][(dt * 16 + l15) * 32 + quad * 8]);
#pragma unroll
    for (int s = 0; s < 2; ++s) {
      uint32_t Ppk[4][2];
#pragma unroll
      for (int mt = 0; mt < 4; ++mt) {
        float p0 = __builtin_amdgcn_exp2f(st[s][mt][0]);
        float p1 = __builtin_amdgcn_exp2f(st[s][mt][1]);
        float p2 = __builtin_amdgcn_exp2f(st[s][mt][2]);
        float p3 = __builtin_amdgcn_exp2f(st[s][mt][3]);
        Ppk[mt][0] = packtr(p0, p1);
        Ppk[mt][1] = packtr(p2, p3);
      }
#pragma unroll
      for (int H = 0; H < 2; ++H) {
        u32x4 d = {Ppk[H][0], Ppk[H][1], Ppk[H + 2][0], Ppk[H + 2][1]};
        bf16x8 pf = __builtin_bit_cast(bf16x8, d);
#pragma unroll
        for (int dt = 0; dt < 4; ++dt) o[s][dt] = MFMA(vf[dt][H], pf, o[s][dt]);
        ol[s] = MFMA(vones, pf, ol[s]);
      }
    }
  }
  uint16_t* ob = Opb + ((size_t)(ks * NH + h) * HDIM) * NTOK;
#pragma unroll
  for (int s = 0; s < 2; ++s) {
    int q = q0 + w * 32 + s * 16 + l15;
#pragma unroll
    for (int dt = 0; dt < 4; ++dt)
#pragma unroll
      for (int rg = 0; rg < 4; ++rg)
        ob[(size_t)(dt * 16 + quad * 4 + rg) * NTOK + q] = f2bf(o[s][dt][rg]);
    if (quad == 0) Lp[(size_t)(ks * NH + h) * NTOK + q] = ol[s][0];
  }
}

// ---------------- combine 2 key-splits, normalize, write bf16 [n][h*64+d] ----------------
__global__ __launch_bounds__(256) void va_combine2(const uint16_t* __restrict__ Opb,
                                                   const float* __restrict__ Lp,
                                                   uint16_t* __restrict__ Ob) {
  __shared__ uint16_t T[64][72];
  const int h = blockIdx.y;
  const int n0 = blockIdx.x * 64;
  const int t = threadIdx.x;
  const int lane = t & 63, c = t >> 6;
  const int n = n0 + lane;
  float lsum = Lp[(size_t)h * NTOK + n] + Lp[(size_t)(NH + h) * NTOK + n];
  const float inv = 1.0f / lsum;
#pragma unroll
  for (int j = 0; j < 16; j += 2) {
    int d = c * 16 + j;
    float r0 = 0.f, r1 = 0.f;
#pragma unroll
    for (int s = 0; s < 2; ++s) {
      const uint16_t* p = Opb + ((size_t)(s * NH + h) * HDIM + d) * NTOK + n;
      r0 += bf2f(p[0]);
      r1 += bf2f(p[NTOK]);
    }
    *(uint32_t*)(&T[lane][d]) = packrd(r0 * inv, r1 * inv);
  }
  __syncthreads();
  const int row = t >> 2, ch = t & 3;
  uint4 a = *(const uint4*)(&T[row][ch * 16]);
  uint4 b = *(const uint4*)(&T[row][ch * 16 + 8]);
  uint16_t* dst = Ob + (size_t)(n0 + row) * DMODEL + h * HDIM + ch * 16;
  *(uint4*)dst = a;
  *(uint4*)(dst + 8) = b;
}

extern "C" void kernel_launch(void* const* d_in, const int* in_sizes, int n_in, void* d_out,
                              int out_size, void* d_ws, size_t ws_size, hipStream_t stream) {
  (void)in_sizes; (void)n_in; (void)out_size; (void)ws_size;
  const float* hidden = (const float*)d_in[0];
  const float* cosb = (const float*)d_in[1];
  const float* sinb = (const float*)d_in[2];
  const float* qkv_w = (const float*)d_in[3];
  const float* qkv_b = (const float*)d_in[4];
  const float* proj_w = (const float*)d_in[5];
  const float* proj_b = (const float*)d_in[6];
  float* out = (float*)d_out;

  char* ws = (char*)d_ws;
  size_t off = 0;
  auto alloc = [&](size_t bytes) {
    void* p = ws + off;
    off += (bytes + 255) & ~(size_t)255;
    return p;
  };
  uint16_t* Abf = (uint16_t*)alloc((size_t)NTOK * DMODEL * 2);
  uint16_t* Wqt = (uint16_t*)alloc((size_t)D3 * DMODEL * 2);
  uint16_t* Wpt = (uint16_t*)alloc((size_t)DMODEL * DMODEL * 2);
  uint16_t* Qb = (uint16_t*)alloc((size_t)NH * NTOK * HDIM * 2);
  uint16_t* Kb = (uint16_t*)alloc((size_t)NH * NTOK * HDIM * 2);
  uint16_t* Vtb = (uint16_t*)alloc((size_t)2 * NH * HDIM * 2048 * 2);  // split planes
  uint16_t* Ob = (uint16_t*)alloc((size_t)NTOK * DMODEL * 2);
  uint16_t* Opb = (uint16_t*)alloc((size_t)2 * NH * HDIM * NTOK * 2);
  float* Lp = (float*)alloc((size_t)2 * NH * NTOK * 4);

  va_cast_bf16<<<(NTOK * DMODEL / 4 + 255) / 256, 256, 0, stream>>>(hidden, Abf,
                                                                    NTOK * DMODEL / 4);
  va_transpose_cast<<<dim3(D3 / 32, DMODEL / 32), 256, 0, stream>>>(qkv_w, Wqt, DMODEL, D3);
  va_transpose_cast<<<dim3(DMODEL / 32, DMODEL / 32), 256, 0, stream>>>(proj_w, Wpt, DMODEL,
                                                                        DMODEL);
  va_gemm_qkv<<<dim3(D3 / 128, NTOK / 128), 256, 0, stream>>>(Abf, Wqt, qkv_b, cosb, sinb, Qb,
                                                              Kb, Vtb);
  va_flash10<<<dim3(64, NH), 256, 0, stream>>>(Qb, Kb, Vtb, Opb, Lp);
  va_combine2<<<dim3(NTOK / 64, NH), 256, 0, stream>>>(Opb, Lp, Ob);
  va_gemm_proj<<<dim3(DMODEL / 128, NTOK / 64), 256, 0, stream>>>(Ob, Wpt, proj_b, out, NTOK,
                                                                  DMODEL, DMODEL);
}

// Round 11
// 199.960 us; speedup vs baseline: 1.0556x; 1.0012x over previous
//
#include <hip/hip_runtime.h>
#include <stdint.h>

#define NTOK 4096
#define NH 12
#define HDIM 64
#define DMODEL 768
#define D3 2304

typedef __attribute__((ext_vector_type(8))) __bf16 bf16x8;
typedef __attribute__((ext_vector_type(4))) float f32x4;
typedef __attribute__((ext_vector_type(4))) unsigned int u32x4;

#define MFMA(a, b, c) __builtin_amdgcn_mfma_f32_16x16x32_bf16((a), (b), (c), 0, 0, 0)

// round-half-up bf16 (0.5-ulp bound, same as RNE)
__device__ __forceinline__ uint16_t f2bf(float f) {
  uint32_t u = __builtin_bit_cast(uint32_t, f) + 0x8000u;
  return (uint16_t)(u >> 16);
}
// pack two floats -> two bf16 in one dword, round-half-up: 2 adds + 1 v_perm
__device__ __forceinline__ uint32_t packrd(float a, float b) {
  uint32_t ua = __builtin_bit_cast(uint32_t, a) + 0x8000u;
  uint32_t ub = __builtin_bit_cast(uint32_t, b) + 0x8000u;
  return __builtin_amdgcn_perm(ub, ua, 0x07060302u);
}
// pack two floats -> two bf16, TRUNCATE (1 op). P only: bias cancels in O/l.
__device__ __forceinline__ uint32_t packtr(float a, float b) {
  return __builtin_amdgcn_perm(__builtin_bit_cast(uint32_t, b), __builtin_bit_cast(uint32_t, a),
                               0x07060302u);
}
__device__ __forceinline__ float bf2f(uint16_t u) {
  uint32_t v = ((uint32_t)u) << 16;
  return __builtin_bit_cast(float, v);
}
// async global->LDS, 16B per lane; lds dest = wave-uniform base + lane*16
__device__ __forceinline__ void gld_lds16(const uint16_t* g, uint16_t* l) {
  __builtin_amdgcn_global_load_lds((const __attribute__((address_space(1))) void*)g,
                                   (__attribute__((address_space(3))) void*)l, 16, 0, 0);
}

// ---------------- cast hidden fp32 -> bf16 ----------------
__global__ void va_cast_bf16(const float* __restrict__ in, uint16_t* __restrict__ out, int n4) {
  int i = blockIdx.x * 256 + threadIdx.x;
  if (i >= n4) return;
  float4 v = ((const float4*)in)[i];
  ((uint2*)out)[i] = make_uint2(packrd(v.x, v.y), packrd(v.z, v.w));
}

// ---------------- transpose + cast: W[K][N] fp32 -> Wt[N][K] bf16 ----------------
__global__ void va_transpose_cast(const float* __restrict__ W, uint16_t* __restrict__ Wt,
                                  int K, int Ncols) {
  __shared__ uint16_t tile[32][36];
  const int t = threadIdx.x;
  const int k0 = blockIdx.y * 32, n0 = blockIdx.x * 32;
  {
    int i = t >> 3, j = (t & 7) * 4;
    float4 v = *(const float4*)(W + (size_t)(k0 + i) * Ncols + n0 + j);
    tile[i][j + 0] = f2bf(v.x);
    tile[i][j + 1] = f2bf(v.y);
    tile[i][j + 2] = f2bf(v.z);
    tile[i][j + 3] = f2bf(v.w);
  }
  __syncthreads();
  {
    int c = t >> 3, kk = (t & 7) * 4;
    uint32_t lo = (uint32_t)tile[kk + 0][c] | ((uint32_t)tile[kk + 1][c] << 16);
    uint32_t hi = (uint32_t)tile[kk + 2][c] | ((uint32_t)tile[kk + 3][c] << 16);
    *(uint2*)(Wt + (size_t)(n0 + c) * K + k0 + kk) = make_uint2(lo, hi);
  }
}

// ---------------- fused QKV GEMM + RoPE + V-plane-permute ----------------
// m97 structure (128x128 tile, BK=32). Epilogue by column-block type:
//   Q/K: RoPE in-register; stored in d-INTERLEAVED pair layout [h][n][2*(d&31)+(d>>5)]
//   (QK^T contracts over d, so any shared d-permutation is free) -> one packed uint32
//   store per rope pair instead of two scalar 2B stores. Flash code is unchanged.
//   V: plane-permuted store for the free-P PV contraction (H=i&1, pos=quad*8+((i>>1)&1)*4+rg).
__global__ __launch_bounds__(256) void va_gemm_qkv(const uint16_t* __restrict__ A,
                                                   const uint16_t* __restrict__ Bt,
                                                   const float* __restrict__ bias,
                                                   const float* __restrict__ cosb,
                                                   const float* __restrict__ sinb,
                                                   uint16_t* __restrict__ Qg,
                                                   uint16_t* __restrict__ Kg,
                                                   uint16_t* __restrict__ Vtg) {
  __shared__ uint16_t As[128 * 32];
  __shared__ uint16_t Bs[128 * 32];
  const int t = threadIdx.x;
  const int w = t >> 6, ln = t & 63, quad = ln >> 4, l15 = ln & 15;
  const int m0 = blockIdx.y * 128, n0 = blockIdx.x * 128;
  const int wm = (w & 1) * 64, wn = (w >> 1) * 64;
  const int srow = t >> 2, scol = (t & 3) * 8;
  f32x4 acc[4][4] = {};
  for (int kk = 0; kk < DMODEL; kk += 32) {
#pragma unroll
    for (int p = 0; p < 2; ++p) {
      gld_lds16(A + (size_t)(m0 + p * 64 + srow) * DMODEL + kk + scol,
                As + (p * 64 + w * 16) * 32);
      gld_lds16(Bt + (size_t)(n0 + p * 64 + srow) * DMODEL + kk + scol,
                Bs + (p * 64 + w * 16) * 32);
    }
    __syncthreads();
    bf16x8 af[4], bfr[4];
#pragma unroll
    for (int i = 0; i < 4; ++i) {
      af[i] = *(const bf16x8*)(As + (wm + i * 16 + l15) * 32 + quad * 8);
      bfr[i] = *(const bf16x8*)(Bs + (wn + i * 16 + l15) * 32 + quad * 8);
    }
#pragma unroll
    for (int i = 0; i < 4; ++i)
#pragma unroll
      for (int j = 0; j < 4; ++j) acc[i][j] = MFMA(af[i], bfr[j], acc[i][j]);
    __syncthreads();
  }
  const int col0 = n0 + wn;          // multiple of 64
  const int type = col0 / DMODEL;    // 0=Q 1=K 2=V
  const int h = (col0 % DMODEL) / HDIM;
  if (type < 2) {
    const float sc = (type == 0) ? (0.125f * 1.4426950408889634f) : 1.0f;
    uint16_t* dst = (type == 0 ? Qg : Kg) + (size_t)h * NTOK * HDIM;
#pragma unroll
    for (int j = 0; j < 2; ++j) {
      const int d = j * 16 + l15, dhi = d + 32;
      const float blo = bias[col0 + d], bhi = bias[col0 + dhi];
#pragma unroll
      for (int i = 0; i < 4; ++i) {
        const int row0 = m0 + wm + i * 16 + quad * 4;
#pragma unroll
        for (int rg = 0; rg < 4; ++rg) {
          const int n = row0 + rg;
          const float a = acc[i][j][rg] + blo;
          const float b = acc[i][j + 2][rg] + bhi;
          const float cl = cosb[(size_t)n * HDIM + d], sl = sinb[(size_t)n * HDIM + d];
          const float ch = cosb[(size_t)n * HDIM + dhi], sh = sinb[(size_t)n * HDIM + dhi];
          *(uint32_t*)(dst + (size_t)n * HDIM + 2 * d) =
              packrd((a * cl - b * sl) * sc, (b * ch + a * sh) * sc);
        }
      }
    }
  } else {
    const int win = (m0 + wm) >> 6;
#pragma unroll
    for (int i = 0; i < 4; ++i) {
      const int H = i & 1, hb = (i >> 1) & 1;
      const int colp = win * 32 + quad * 8 + hb * 4;
#pragma unroll
      for (int j = 0; j < 4; ++j) {
        const int d = j * 16 + l15;
        const float bb = bias[col0 + d];
        uint32_t u0 = packrd(acc[i][j][0] + bb, acc[i][j][1] + bb);
        uint32_t u1 = packrd(acc[i][j][2] + bb, acc[i][j][3] + bb);
        *(uint2*)(Vtg + (((size_t)H * NH + h) * HDIM + d) * 2048 + colp) = make_uint2(u0, u1);
      }
    }
  }
}

// ---------------- m97-style GEMM (proj): C = A @ Bt^T + bias, fp32 out ----------------
__global__ __launch_bounds__(256) void va_gemm_proj(const uint16_t* __restrict__ A,
                                                    const uint16_t* __restrict__ Bt,
                                                    const float* __restrict__ bias,
                                                    float* __restrict__ C, int M, int Nc, int K) {
  __shared__ uint16_t As[64 * 32];
  __shared__ uint16_t Bs[128 * 32];
  const int t = threadIdx.x;
  const int w = t >> 6, ln = t & 63, quad = ln >> 4, l15 = ln & 15;
  const int m0 = blockIdx.y * 64, n0 = blockIdx.x * 128;
  const int wn = w * 32;
  const int srow = t >> 2, scol = (t & 3) * 8;
  f32x4 acc[4][2] = {};
  for (int kk = 0; kk < K; kk += 32) {
    if (srow < 64)
      gld_lds16(A + (size_t)(m0 + srow) * K + kk + scol, As + w * 16 * 32);
#pragma unroll
    for (int p = 0; p < 2; ++p)
      gld_lds16(Bt + (size_t)(n0 + p * 64 + srow) * K + kk + scol, Bs + (p * 64 + w * 16) * 32);
    __syncthreads();
    bf16x8 af[4], bfr[2];
#pragma unroll
    for (int i = 0; i < 4; ++i) af[i] = *(const bf16x8*)(As + (i * 16 + l15) * 32 + quad * 8);
#pragma unroll
    for (int j = 0; j < 2; ++j)
      bfr[j] = *(const bf16x8*)(Bs + (wn + j * 16 + l15) * 32 + quad * 8);
#pragma unroll
    for (int i = 0; i < 4; ++i)
#pragma unroll
      for (int j = 0; j < 2; ++j) acc[i][j] = MFMA(af[i], bfr[j], acc[i][j]);
    __syncthreads();
  }
#pragma unroll
  for (int i = 0; i < 4; ++i) {
    int row = m0 + i * 16 + quad * 4;
#pragma unroll
    for (int j = 0; j < 2; ++j) {
      int col = n0 + wn + j * 16 + l15;
      float b = bias[col];
#pragma unroll
      for (int rg = 0; rg < 4; ++rg) C[(size_t)(row + rg) * Nc + col] = acc[i][j][rg] + b;
    }
  }
}

// ---------------- Flash attention v11 ----------------
// Grid: x = qb(32) | ks(2)<<5, y = head. 768 blocks = 3/CU exactly. 32 iters of 64-key tiles.
// Free-P PV transform + split-plane V + l via ones-MFMA. Opb written ROW-MAJOR [ks][q][768]
// (packed uint2) so the combine kernel is a pure streaming pass.
__global__ __launch_bounds__(256, 3) void va_flash11(const uint16_t* __restrict__ Qg,
                                                     const uint16_t* __restrict__ Kg,
                                                     const uint16_t* __restrict__ Vtg,
                                                     uint16_t* __restrict__ Opb,
                                                     float* __restrict__ Lp) {
  __shared__ uint16_t Ks[2][2][64 * 32];  // [dbuf][d-half][64 keys x 32 d]
  __shared__ uint16_t Vs[2][2][64 * 32];  // [dbuf][key-plane H][64 d x 32 permuted keys]
  const int t = threadIdx.x;
  const int w = t >> 6, ln = t & 63, quad = ln >> 4, l15 = ln & 15;
  const int h = blockIdx.y;
  const int qb = blockIdx.x & 31, ks = blockIdx.x >> 5;
  const int q0 = qb * 128, key0 = ks * 2048;

  bf16x8 qf[2][2];
#pragma unroll
  for (int s = 0; s < 2; ++s)
#pragma unroll
    for (int c = 0; c < 2; ++c)
      qf[s][c] = *(const bf16x8*)(Qg + ((size_t)h * NTOK + q0 + w * 32 + s * 16 + l15) * HDIM +
                                  c * 32 + quad * 8);
  const u32x4 onesu = {0x3F803F80u, 0x3F803F80u, 0x3F803F80u, 0x3F803F80u};
  const bf16x8 vones = __builtin_bit_cast(bf16x8, onesu);
  f32x4 o[2][4] = {};
  f32x4 ol[2] = {};  // ones-MFMA accumulator: all regs hold l[query l15]
  const uint16_t* Kst =
      Kg + ((size_t)h * NTOK + key0 + w * 16 + (ln >> 2)) * HDIM + (ln & 3) * 8;
  const uint16_t* Vst0 =
      Vtg + (((size_t)0 * NH + h) * HDIM + w * 16 + (ln >> 2)) * 2048 + ks * 1024 + (ln & 3) * 8;
  const uint16_t* Vst1 =
      Vtg + (((size_t)1 * NH + h) * HDIM + w * 16 + (ln >> 2)) * 2048 + ks * 1024 + (ln & 3) * 8;

  gld_lds16(Kst, &Ks[0][0][w * 16 * 32]);
  gld_lds16(Kst + 32, &Ks[0][1][w * 16 * 32]);
  gld_lds16(Vst0, &Vs[0][0][w * 16 * 32]);
  gld_lds16(Vst1, &Vs[0][1][w * 16 * 32]);

  for (int kt = 0; kt < 32; ++kt) {
    __syncthreads();
    const int cur = kt & 1;
    if (kt < 31) {
      Kst += 64 * HDIM;
      Vst0 += 32;
      Vst1 += 32;
      gld_lds16(Kst, &Ks[cur ^ 1][0][w * 16 * 32]);
      gld_lds16(Kst + 32, &Ks[cur ^ 1][1][w * 16 * 32]);
      gld_lds16(Vst0, &Vs[cur ^ 1][0][w * 16 * 32]);
      gld_lds16(Vst1, &Vs[cur ^ 1][1][w * 16 * 32]);
    }
    f32x4 st[2][4];
#pragma unroll
    for (int mt = 0; mt < 4; ++mt) {
      bf16x8 ka0 = *(const bf16x8*)(&Ks[cur][0][(mt * 16 + l15) * 32 + quad * 8]);
      bf16x8 ka1 = *(const bf16x8*)(&Ks[cur][1][(mt * 16 + l15) * 32 + quad * 8]);
#pragma unroll
      for (int s = 0; s < 2; ++s) {
        f32x4 z = {};
        z = MFMA(ka0, qf[s][0], z);
        st[s][mt] = MFMA(ka1, qf[s][1], z);
      }
    }
    bf16x8 vf[4][2];
#pragma unroll
    for (int dt = 0; dt < 4; ++dt)
#pragma unroll
      for (int H = 0; H < 2; ++H)
        vf[dt][H] = *(const bf16x8*)(&Vs[cur][H][(dt * 16 + l15) * 32 + quad * 8]);
#pragma unroll
    for (int s = 0; s < 2; ++s) {
      uint32_t Ppk[4][2];
#pragma unroll
      for (int mt = 0; mt < 4; ++mt) {
        float p0 = __builtin_amdgcn_exp2f(st[s][mt][0]);
        float p1 = __builtin_amdgcn_exp2f(st[s][mt][1]);
        float p2 = __builtin_amdgcn_exp2f(st[s][mt][2]);
        float p3 = __builtin_amdgcn_exp2f(st[s][mt][3]);
        Ppk[mt][0] = packtr(p0, p1);
        Ppk[mt][1] = packtr(p2, p3);
      }
#pragma unroll
      for (int H = 0; H < 2; ++H) {
        u32x4 d = {Ppk[H][0], Ppk[H][1], Ppk[H + 2][0], Ppk[H + 2][1]};
        bf16x8 pf = __builtin_bit_cast(bf16x8, d);
#pragma unroll
        for (int dt = 0; dt < 4; ++dt) o[s][dt] = MFMA(vf[dt][H], pf, o[s][dt]);
        ol[s] = MFMA(vones, pf, ol[s]);
      }
    }
  }
  // epilogue: row-major unnormalized O (bf16, packed uint2) + per-query l (fp32)
#pragma unroll
  for (int s = 0; s < 2; ++s) {
    const int q = q0 + w * 32 + s * 16 + l15;
    uint16_t* row = Opb + ((size_t)ks * NTOK + q) * DMODEL + h * HDIM + quad * 4;
#pragma unroll
    for (int dt = 0; dt < 4; ++dt) {
      uint32_t u0 = packrd(o[s][dt][0], o[s][dt][1]);
      uint32_t u1 = packrd(o[s][dt][2], o[s][dt][3]);
      *(uint2*)(row + dt * 16) = make_uint2(u0, u1);
    }
    if (quad == 0) Lp[(size_t)(ks * NH + h) * NTOK + q] = ol[s][0];
  }
}

// ---------------- combine 2 key-splits (streaming): Ob[n][768] bf16 ----------------
__global__ __launch_bounds__(256) void va_combine2r(const uint16_t* __restrict__ Opb,
                                                    const float* __restrict__ Lp,
                                                    uint16_t* __restrict__ Ob) {
  const int idx = blockIdx.x * 256 + threadIdx.x;  // uint4 chunk index (8 bf16)
  const int n = idx / 96, c = idx % 96;
  const int h = c >> 3;
  const float inv =
      1.0f / (Lp[(size_t)h * NTOK + n] + Lp[((size_t)NH + h) * NTOK + n]);
  const uint16_t* p0 = Opb + (size_t)n * DMODEL + c * 8;
  const uint16_t* p1 = Opb + ((size_t)NTOK + n) * DMODEL + c * 8;
  uint16_t a[8], b[8];
  *(uint4*)a = *(const uint4*)p0;
  *(uint4*)b = *(const uint4*)p1;
  uint32_t out[4];
#pragma unroll
  for (int j = 0; j < 8; j += 2) {
    float r0 = (bf2f(a[j]) + bf2f(b[j])) * inv;
    float r1 = (bf2f(a[j + 1]) + bf2f(b[j + 1])) * inv;
    out[j >> 1] = packrd(r0, r1);
  }
  *(uint4*)(Ob + (size_t)n * DMODEL + c * 8) = *(uint4*)out;
}

extern "C" void kernel_launch(void* const* d_in, const int* in_sizes, int n_in, void* d_out,
                              int out_size, void* d_ws, size_t ws_size, hipStream_t stream) {
  (void)in_sizes; (void)n_in; (void)out_size; (void)ws_size;
  const float* hidden = (const float*)d_in[0];
  const float* cosb = (const float*)d_in[1];
  const float* sinb = (const float*)d_in[2];
  const float* qkv_w = (const float*)d_in[3];
  const float* qkv_b = (const float*)d_in[4];
  const float* proj_w = (const float*)d_in[5];
  const float* proj_b = (const float*)d_in[6];
  float* out = (float*)d_out;

  char* ws = (char*)d_ws;
  size_t off = 0;
  auto alloc = [&](size_t bytes) {
    void* p = ws + off;
    off += (bytes + 255) & ~(size_t)255;
    return p;
  };
  uint16_t* Abf = (uint16_t*)alloc((size_t)NTOK * DMODEL * 2);
  uint16_t* Wqt = (uint16_t*)alloc((size_t)D3 * DMODEL * 2);
  uint16_t* Wpt = (uint16_t*)alloc((size_t)DMODEL * DMODEL * 2);
  uint16_t* Qb = (uint16_t*)alloc((size_t)NH * NTOK * HDIM * 2);
  uint16_t* Kb = (uint16_t*)alloc((size_t)NH * NTOK * HDIM * 2);
  uint16_t* Vtb = (uint16_t*)alloc((size_t)2 * NH * HDIM * 2048 * 2);  // split planes
  uint16_t* Ob = (uint16_t*)alloc((size_t)NTOK * DMODEL * 2);
  uint16_t* Opb = (uint16_t*)alloc((size_t)2 * NTOK * DMODEL * 2);     // row-major per split
  float* Lp = (float*)alloc((size_t)2 * NH * NTOK * 4);

  va_cast_bf16<<<(NTOK * DMODEL / 4 + 255) / 256, 256, 0, stream>>>(hidden, Abf,
                                                                    NTOK * DMODEL / 4);
  va_transpose_cast<<<dim3(D3 / 32, DMODEL / 32), 256, 0, stream>>>(qkv_w, Wqt, DMODEL, D3);
  va_transpose_cast<<<dim3(DMODEL / 32, DMODEL / 32), 256, 0, stream>>>(proj_w, Wpt, DMODEL,
                                                                        DMODEL);
  va_gemm_qkv<<<dim3(D3 / 128, NTOK / 128), 256, 0, stream>>>(Abf, Wqt, qkv_b, cosb, sinb, Qb,
                                                              Kb, Vtb);
  va_flash11<<<dim3(64, NH), 256, 0, stream>>>(Qb, Kb, Vtb, Opb, Lp);
  va_combine2r<<<(NTOK * DMODEL / 8) / 256, 256, 0, stream>>>(Opb, Lp, Ob);
  va_gemm_proj<<<dim3(DMODEL / 128, NTOK / 64), 256, 0, stream>>>(Ob, Wpt, proj_b, out, NTOK,
                                                                  DMODEL, DMODEL);
}